// Round 1
// baseline (870.718 us; speedup 1.0000x reference)
//
#include <hip/hip_runtime.h>

// Problem constants
#define BATCH 8
#define SEQ   256
#define VOC   50257
#define DIM   128
#define NH    256
#define LOGITS_ELEMS 102926336ULL  // 8*256*50257

constexpr float PHI_F   = 1.61803398874989485f;
constexpr float SCALE_F = (float)(4096.0 / 6.283185307179586);   // RES/(2*pi)
constexpr float STEP_F  = (float)(6.283185307179586 / 4096.0);   // 2*pi/RES

__device__ __forceinline__ unsigned short f2bf(float f) {
    unsigned int u = __float_as_uint(f);
    u = (u + 0x7fffu + ((u >> 16) & 1u)) >> 16;   // RNE
    return (unsigned short)u;
}

// ---------------------------------------------------------------------------
// fused prep:
//   bid 0..7      : recurrence (one block per batch), gathers emb directly,
//                   16-step A/B register prefetch. Runs overlapped with the
//                   rest of the grid (placed FIRST so it dispatches earliest).
//   bid 8..6290   : out_w fp32 -> bf16
//   bid 6291..7058: transpose layer weights wt[i][d][n], wrt/wit[i][n][d]
// ---------------------------------------------------------------------------
__global__ __launch_bounds__(256) void prep_kernel(
        const float* __restrict__ emb,
        const int*   __restrict__ ids,
        const float* __restrict__ W,
        const float* __restrict__ Wr,
        const float* __restrict__ Wi,
        const float* __restrict__ outw,
        unsigned short* __restrict__ outw_bf,
        float* __restrict__ wt,
        float* __restrict__ wrt,
        float* __restrict__ wit,
        float* __restrict__ X0,
        float* __restrict__ out) {
    int bid = blockIdx.x;
    int tid = threadIdx.x;
    if (bid < 8) {
        // ---------------- recurrence ----------------
        __shared__ int ids_s[256];
        ids_s[tid] = ids[bid * 256 + tid];
        __syncthreads();
        if (tid >= 128) return;
        const int b = bid, d = tid;
        float wA[16], bA[16], wB[16], bB[16];
        #pragma unroll
        for (int u = 0; u < 16; ++u) {
            const float* e = emb + (size_t)ids_s[u] * 256 + d;
            wA[u] = e[0]; bA[u] = e[128];
        }
        float hr = 0.0f, hi = 0.0f;
        float* X0p = X0 + b * 128 + d;
        for (int t0 = 0; t0 < 256; t0 += 32) {
            // prefetch steps t0+16 .. t0+31 into B
            #pragma unroll
            for (int u = 0; u < 16; ++u) {
                const float* e = emb + (size_t)ids_s[t0 + 16 + u] * 256 + d;
                wB[u] = e[0]; bB[u] = e[128];
            }
            // compute steps t0 .. t0+15 from A
            #pragma unroll
            for (int u = 0; u < 16; ++u) {
                int t = t0 + u;
                float tphi = (float)t * PHI_F;
                float th = (hr + hi) / (1.0f + fabsf(wA[u])) + bA[u] + tphi;
                int idx = ((int)rintf(th * SCALE_F)) & 4095;
                float ang = (float)idx * STEP_F;
                hi = __sinf(ang); hr = __cosf(ang);
                X0p[t * 1024] = hr + hi;
            }
            // prefetch steps t0+32 .. t0+47 into A
            if (t0 + 32 < 256) {
                #pragma unroll
                for (int u = 0; u < 16; ++u) {
                    const float* e = emb + (size_t)ids_s[t0 + 32 + u] * 256 + d;
                    wA[u] = e[0]; bA[u] = e[128];
                }
            }
            // compute steps t0+16 .. t0+31 from B
            #pragma unroll
            for (int u = 0; u < 16; ++u) {
                int t = t0 + 16 + u;
                float tphi = (float)t * PHI_F;
                float th = (hr + hi) / (1.0f + fabsf(wB[u])) + bB[u] + tphi;
                int idx = ((int)rintf(th * SCALE_F)) & 4095;
                float ang = (float)idx * STEP_F;
                hi = __sinf(ang); hr = __cosf(ang);
                X0p[t * 1024] = hr + hi;
            }
        }
        out[LOGITS_ELEMS + b * 128 + d] = hr;
        out[LOGITS_ELEMS + 1024 + b * 128 + d] = hi;
    } else if (bid < 6291) {
        // ---------------- out_w fp32 -> bf16 ----------------
        int i4 = (bid - 8) * 256 + tid;
        if (i4 < (VOC * DIM) / 4) {
            float4 v = ((const float4*)outw)[i4];
            unsigned int lo = ((unsigned)f2bf(v.y) << 16) | f2bf(v.x);
            unsigned int hi = ((unsigned)f2bf(v.w) << 16) | f2bf(v.z);
            ((uint2*)outw_bf)[i4] = make_uint2(lo, hi);
        }
    } else {
        // ---------------- weight transposes ----------------
        int e = (bid - 6291) * 256 + tid;        // < 196608 exactly
        int tns = e >> 16;                        // 0:W 1:Wr 2:Wi
        int r = e & 65535;
        int i = r >> 15, rem = r & 32767;
        if (tns == 0) {
            int dd = rem >> 8, n = rem & 255;
            wt[r] = W[(i * 256 + n) * 128 + dd];
        } else if (tns == 1) {
            int n = rem >> 7, dd = rem & 127;
            wrt[r] = Wr[(i * 128 + dd) * 256 + n];
        } else {
            int n = rem >> 7, dd = rem & 127;
            wit[r] = Wi[(i * 128 + dd) * 256 + n];
        }
    }
}

// ---------------------------------------------------------------------------
// layers: 256 blocks (one per t) x 256 threads; 8 rows (all b) per block.
// LDS layouts are r-fastest with stride 12 floats (48 B):
//   - float4 reads are 16B-aligned broadcasts (conflict-free)
//   - lane-stride-48B ds_write_b128 covers all 32 banks (conflict-free)
// ---------------------------------------------------------------------------
__global__ __launch_bounds__(256) void layers_kernel(
        const float* __restrict__ X0,
        const float* __restrict__ wt,
        const float* __restrict__ wrt,
        const float* __restrict__ wit,
        const float* __restrict__ lb,
        unsigned short* __restrict__ X2bf) {
    __shared__ __align__(16) float xs[128 * 12];    // [d][r] stride 12
    __shared__ __align__(16) float csh[256 * 12];   // [n][r] stride 12
    __shared__ __align__(16) float snh[256 * 12];
    __shared__ __align__(16) float part[128 * 12];  // [d][r] stride 12
    int tid = threadIdx.x, t = blockIdx.x;
    float tphi = (float)t * PHI_F;
    {   // load X0 tile [r][d] and transpose into xs[d][r]
        float4 v = ((const float4*)(X0 + t * 1024))[tid];
        int r = tid >> 5, d0 = (tid & 31) << 2;
        xs[(d0 + 0) * 12 + r] = v.x;
        xs[(d0 + 1) * 12 + r] = v.y;
        xs[(d0 + 2) * 12 + r] = v.z;
        xs[(d0 + 3) * 12 + r] = v.w;
    }
    __syncthreads();
    for (int i = 0; i < 2; ++i) {
        // phase 1: th[r][n] = x[r] . W[n] + b[n] + tphi ; sn/cs lookup
        const float* wti = wt + i * 32768;
        float acc[8] = {0,0,0,0,0,0,0,0};
        int n = tid;
        #pragma unroll 4
        for (int d = 0; d < 128; ++d) {
            float wv = wti[d * 256 + n];
            float4 x0 = *(const float4*)&xs[d * 12];
            float4 x1 = *(const float4*)&xs[d * 12 + 4];
            acc[0] += x0.x * wv; acc[1] += x0.y * wv;
            acc[2] += x0.z * wv; acc[3] += x0.w * wv;
            acc[4] += x1.x * wv; acc[5] += x1.y * wv;
            acc[6] += x1.z * wv; acc[7] += x1.w * wv;
        }
        float bv = lb[i * 256 + n];
        float cs[8], sn[8];
        #pragma unroll
        for (int r = 0; r < 8; ++r) {
            float th = acc[r] + bv + tphi;
            int idx = ((int)rintf(th * SCALE_F)) & 4095;
            float ang = (float)idx * STEP_F;
            cs[r] = __cosf(ang);
            sn[r] = __sinf(ang);
        }
        *(float4*)&csh[n * 12]     = make_float4(cs[0], cs[1], cs[2], cs[3]);
        *(float4*)&csh[n * 12 + 4] = make_float4(cs[4], cs[5], cs[6], cs[7]);
        *(float4*)&snh[n * 12]     = make_float4(sn[0], sn[1], sn[2], sn[3]);
        *(float4*)&snh[n * 12 + 4] = make_float4(sn[4], sn[5], sn[6], sn[7]);
        __syncthreads();
        // phase 2: o[r][d] = cs . Wr[d] + sn . Wi[d] ; x += silu(o)
        int d2 = tid & 127, h = tid >> 7;
        const float* wri = wrt + i * 32768;
        const float* wii = wit + i * 32768;
        float a2[8] = {0,0,0,0,0,0,0,0};
        int n0 = h << 7;
        #pragma unroll 2
        for (int nn = 0; nn < 128; ++nn) {
            int nidx = n0 + nn;
            float rv = wri[nidx * 128 + d2];
            float iv = wii[nidx * 128 + d2];
            float4 c0 = *(const float4*)&csh[nidx * 12];
            float4 c1 = *(const float4*)&csh[nidx * 12 + 4];
            float4 s0 = *(const float4*)&snh[nidx * 12];
            float4 s1 = *(const float4*)&snh[nidx * 12 + 4];
            a2[0] += c0.x * rv + s0.x * iv;
            a2[1] += c0.y * rv + s0.y * iv;
            a2[2] += c0.z * rv + s0.z * iv;
            a2[3] += c0.w * rv + s0.w * iv;
            a2[4] += c1.x * rv + s1.x * iv;
            a2[5] += c1.y * rv + s1.y * iv;
            a2[6] += c1.z * rv + s1.z * iv;
            a2[7] += c1.w * rv + s1.w * iv;
        }
        if (h) {
            *(float4*)&part[d2 * 12]     = make_float4(a2[0], a2[1], a2[2], a2[3]);
            *(float4*)&part[d2 * 12 + 4] = make_float4(a2[4], a2[5], a2[6], a2[7]);
        }
        __syncthreads();
        if (!h) {
            float4 p0 = *(const float4*)&part[d2 * 12];
            float4 p1 = *(const float4*)&part[d2 * 12 + 4];
            float pr[8] = {p0.x, p0.y, p0.z, p0.w, p1.x, p1.y, p1.z, p1.w};
            float4 xv0 = *(const float4*)&xs[d2 * 12];
            float4 xv1 = *(const float4*)&xs[d2 * 12 + 4];
            float xv[8] = {xv0.x, xv0.y, xv0.z, xv0.w, xv1.x, xv1.y, xv1.z, xv1.w};
            #pragma unroll
            for (int r = 0; r < 8; ++r) {
                float o = a2[r] + pr[r];
                float sg = 1.0f / (1.0f + __expf(-o));
                xv[r] += o * sg;
            }
            *(float4*)&xs[d2 * 12]     = make_float4(xv[0], xv[1], xv[2], xv[3]);
            *(float4*)&xs[d2 * 12 + 4] = make_float4(xv[4], xv[5], xv[6], xv[7]);
        }
        __syncthreads();
    }
    // pack to bf16, restoring [r][d] order
    int r = tid >> 5, d0 = (tid & 31) << 2;
    float v0 = xs[(d0 + 0) * 12 + r];
    float v1 = xs[(d0 + 1) * 12 + r];
    float v2 = xs[(d0 + 2) * 12 + r];
    float v3 = xs[(d0 + 3) * 12 + r];
    unsigned int lo = ((unsigned)f2bf(v1) << 16) | f2bf(v0);
    unsigned int hi = ((unsigned)f2bf(v3) << 16) | f2bf(v2);
    ((uint2*)(X2bf + t * 1024))[tid] = make_uint2(lo, hi);
}

// ---------------------------------------------------------------------------
// logits GEMM: C(2048 x 50257) = X2(2048x128,bf16) * out_w^T(bf16)
// M-tile 256, N-tile 256, 1024 threads = 16 waves (4x4), wave = 64x64
// ---------------------------------------------------------------------------
typedef short bhalf8 __attribute__((ext_vector_type(8)));
typedef float fx4    __attribute__((ext_vector_type(4)));

__global__ __launch_bounds__(1024) void gemm_kernel(
        const unsigned short* __restrict__ X2bf,
        const unsigned short* __restrict__ outw_bf,
        float* __restrict__ out) {
    __shared__ __align__(16) unsigned short Ash[32768];   // 64 KB, fragment-permuted
    int tid = threadIdx.x;
    int mt = blockIdx.x & 7;
    int nt = blockIdx.x >> 3;
    // stage A tile permuted into MFMA fragment order: slot = (msub*4+ks)*64+lane
    for (int s = tid; s < 4096; s += 1024) {
        int blk = s >> 6, ln = s & 63;
        int msub = blk >> 2, ks = blk & 3;
        int row = mt * 256 + msub * 16 + (ln & 15);
        int kel = ks * 32 + ((ln >> 4) << 3);
        ((int4*)Ash)[s] = *(const int4*)(X2bf + row * 128 + kel);
    }
    __syncthreads();
    int lane = tid & 63, wave = tid >> 6;
    int wm = wave >> 2, wn = wave & 3;
    int ln15 = lane & 15, lq = lane >> 4;
    fx4 acc[4][4] = {};
    const bhalf8* Af = (const bhalf8*)Ash;
    for (int ks = 0; ks < 4; ++ks) {
        bhalf8 a0 = Af[((wm * 4 + 0) * 4 + ks) * 64 + lane];
        bhalf8 a1 = Af[((wm * 4 + 1) * 4 + ks) * 64 + lane];
        bhalf8 a2 = Af[((wm * 4 + 2) * 4 + ks) * 64 + lane];
        bhalf8 a3 = Af[((wm * 4 + 3) * 4 + ks) * 64 + lane];
        #pragma unroll
        for (int j = 0; j < 4; ++j) {
            int v = nt * 256 + wn * 64 + j * 16 + ln15;
            bhalf8 bfr = {};
            if (v < VOC)
                bfr = *(const bhalf8*)(outw_bf + v * 128 + ks * 32 + lq * 8);
            acc[0][j] = __builtin_amdgcn_mfma_f32_16x16x32_bf16(a0, bfr, acc[0][j], 0, 0, 0);
            acc[1][j] = __builtin_amdgcn_mfma_f32_16x16x32_bf16(a1, bfr, acc[1][j], 0, 0, 0);
            acc[2][j] = __builtin_amdgcn_mfma_f32_16x16x32_bf16(a2, bfr, acc[2][j], 0, 0, 0);
            acc[3][j] = __builtin_amdgcn_mfma_f32_16x16x32_bf16(a3, bfr, acc[3][j], 0, 0, 0);
        }
    }
    // store: C layout col=lane&15, row=(lane>>4)*4+reg ; out[b][t][v]
    // nontemporal: logits are write-once, never re-read -> don't thrash L2
    #pragma unroll
    for (int i = 0; i < 4; ++i) {
        #pragma unroll
        for (int j = 0; j < 4; ++j) {
            int v = nt * 256 + wn * 64 + j * 16 + ln15;
            if (v < VOC) {
                int rbase = mt * 256 + wm * 64 + i * 16 + lq * 4;
                int tt = rbase >> 3;               // same t for all 4 regs
                int b0 = rbase & 7;
                size_t rowoff = (size_t)tt * VOC + v;
                #pragma unroll
                for (int rg = 0; rg < 4; ++rg) {
                    __builtin_nontemporal_store(
                        acc[i][j][rg],
                        out + (size_t)(b0 + rg) * (SEQ * (size_t)VOC) + rowoff);
                }
            }
        }
    }
}

// ---------------------------------------------------------------------------
extern "C" void kernel_launch(void* const* d_in, const int* in_sizes, int n_in,
                              void* d_out, int out_size, void* d_ws, size_t ws_size,
                              hipStream_t stream) {
    const int*   ids  = (const int*)d_in[0];
    const float* emb  = (const float*)d_in[1];
    const float* W    = (const float*)d_in[2];
    const float* lb   = (const float*)d_in[3];
    const float* Wr   = (const float*)d_in[4];
    const float* Wi   = (const float*)d_in[5];
    const float* outw = (const float*)d_in[6];
    float* out = (float*)d_out;
    char* ws = (char*)d_ws;

    unsigned short* outw_bf = (unsigned short*)ws;            // 12,865,792 B
    float* wt    = (float*)(ws + 12865792);                   // 262,144 B
    float* wrt   = wt + 65536;                                // 262,144 B
    float* wit   = wrt + 65536;                               // 262,144 B
    float* X0    = wit + 65536;                               // 1,048,576 B
    unsigned short* X2bf = (unsigned short*)(X0 + 262144);    // 524,288 B

    prep_kernel<<<7059, 256, 0, stream>>>(emb, ids, W, Wr, Wi, outw,
                                          outw_bf, wt, wrt, wit, X0, out);
    layers_kernel<<<256, 256, 0, stream>>>(X0, wt, wrt, wit, lb, X2bf);
    gemm_kernel<<<8 * 197, 1024, 0, stream>>>(X2bf, outw_bf, out);
}

// Round 2
// 591.300 us; speedup vs baseline: 1.4725x; 1.4725x over previous
//
#include <hip/hip_runtime.h>

// Problem constants
#define BATCH 8
#define SEQ   256
#define VOC   50257
#define DIM   128
#define NH    256
#define LOGITS_ELEMS 102926336ULL  // 8*256*50257

constexpr float PHI_F   = 1.61803398874989485f;
constexpr float SCALE_F = (float)(4096.0 / 6.283185307179586);   // RES/(2*pi)
constexpr float STEP_F  = (float)(6.283185307179586 / 4096.0);   // 2*pi/RES

__device__ __forceinline__ unsigned short f2bf(float f) {
    unsigned int u = __float_as_uint(f);
    u = (u + 0x7fffu + ((u >> 16) & 1u)) >> 16;   // RNE
    return (unsigned short)u;
}

// ---------------------------------------------------------------------------
// fused prep:
//   bid 0..7      : recurrence (one block per batch), gathers emb directly,
//                   16-step A/B register prefetch
//   bid 8..6290   : out_w fp32 -> bf16
//   bid 6291..7058: transpose layer weights wt[i][d][n], wrt/wit[i][n][d]
// ---------------------------------------------------------------------------
__global__ __launch_bounds__(256) void prep_kernel(
        const float* __restrict__ emb,
        const int*   __restrict__ ids,
        const float* __restrict__ W,
        const float* __restrict__ Wr,
        const float* __restrict__ Wi,
        const float* __restrict__ outw,
        unsigned short* __restrict__ outw_bf,
        float* __restrict__ wt,
        float* __restrict__ wrt,
        float* __restrict__ wit,
        float* __restrict__ X0,
        float* __restrict__ out) {
    int bid = blockIdx.x;
    int tid = threadIdx.x;
    if (bid < 8) {
        __shared__ int ids_s[256];
        ids_s[tid] = ids[bid * 256 + tid];
        __syncthreads();
        if (tid >= 128) return;
        const int b = bid, d = tid;
        float wA[16], bA[16], wB[16], bB[16];
        #pragma unroll
        for (int u = 0; u < 16; ++u) {
            const float* e = emb + (size_t)ids_s[u] * 256 + d;
            wA[u] = e[0]; bA[u] = e[128];
        }
        float hr = 0.0f, hi = 0.0f;
        float* X0p = X0 + b * 128 + d;
        for (int t0 = 0; t0 < 256; t0 += 32) {
            #pragma unroll
            for (int u = 0; u < 16; ++u) {
                const float* e = emb + (size_t)ids_s[t0 + 16 + u] * 256 + d;
                wB[u] = e[0]; bB[u] = e[128];
            }
            #pragma unroll
            for (int u = 0; u < 16; ++u) {
                int t = t0 + u;
                float tphi = (float)t * PHI_F;
                float th = (hr + hi) / (1.0f + fabsf(wA[u])) + bA[u] + tphi;
                int idx = ((int)rintf(th * SCALE_F)) & 4095;
                float ang = (float)idx * STEP_F;
                hi = __sinf(ang); hr = __cosf(ang);
                X0p[t * 1024] = hr + hi;
            }
            if (t0 + 32 < 256) {
                #pragma unroll
                for (int u = 0; u < 16; ++u) {
                    const float* e = emb + (size_t)ids_s[t0 + 32 + u] * 256 + d;
                    wA[u] = e[0]; bA[u] = e[128];
                }
            }
            #pragma unroll
            for (int u = 0; u < 16; ++u) {
                int t = t0 + 16 + u;
                float tphi = (float)t * PHI_F;
                float th = (hr + hi) / (1.0f + fabsf(wB[u])) + bB[u] + tphi;
                int idx = ((int)rintf(th * SCALE_F)) & 4095;
                float ang = (float)idx * STEP_F;
                hi = __sinf(ang); hr = __cosf(ang);
                X0p[t * 1024] = hr + hi;
            }
        }
        out[LOGITS_ELEMS + b * 128 + d] = hr;
        out[LOGITS_ELEMS + 1024 + b * 128 + d] = hi;
    } else if (bid < 6291) {
        int i4 = (bid - 8) * 256 + tid;
        if (i4 < (VOC * DIM) / 4) {
            float4 v = ((const float4*)outw)[i4];
            unsigned int lo = ((unsigned)f2bf(v.y) << 16) | f2bf(v.x);
            unsigned int hi = ((unsigned)f2bf(v.w) << 16) | f2bf(v.z);
            ((uint2*)outw_bf)[i4] = make_uint2(lo, hi);
        }
    } else {
        int e = (bid - 6291) * 256 + tid;        // < 196608 exactly
        int tns = e >> 16;                        // 0:W 1:Wr 2:Wi
        int r = e & 65535;
        int i = r >> 15, rem = r & 32767;
        if (tns == 0) {
            int dd = rem >> 8, n = rem & 255;
            wt[r] = W[(i * 256 + n) * 128 + dd];
        } else if (tns == 1) {
            int n = rem >> 7, dd = rem & 127;
            wrt[r] = Wr[(i * 128 + dd) * 256 + n];
        } else {
            int n = rem >> 7, dd = rem & 127;
            wit[r] = Wi[(i * 128 + dd) * 256 + n];
        }
    }
}

// ---------------------------------------------------------------------------
// layers: 256 blocks (one per t) x 1024 threads (16 waves/CU = 4/SIMD).
// phase 1 split over 4 d-chunks (q1), phase 2 split over 8 n-chunks (q2);
// partial sums reduced through LDS. Accumulation order (d ascending,
// nn ascending) preserved within and across chunks.
// ---------------------------------------------------------------------------
__global__ __launch_bounds__(1024) void layers_kernel(
        const float* __restrict__ X0,
        const float* __restrict__ wt,
        const float* __restrict__ wrt,
        const float* __restrict__ wit,
        const float* __restrict__ lb,
        unsigned short* __restrict__ X2bf) {
    __shared__ __align__(16) float xs[128 * 12];    // [d][r] stride 12
    __shared__ __align__(16) float csh[256 * 12];   // [n][r] stride 12
    __shared__ __align__(16) float snh[256 * 12];
    __shared__ __align__(16) float red[7168];       // 28 KB reduce scratch
    int tid = threadIdx.x, t = blockIdx.x;
    float tphi = (float)t * PHI_F;
    if (tid < 256) {   // load X0 tile [r][d] -> xs[d][r]
        float4 v = ((const float4*)(X0 + t * 1024))[tid];
        int r = tid >> 5, d0 = (tid & 31) << 2;
        xs[(d0 + 0) * 12 + r] = v.x;
        xs[(d0 + 1) * 12 + r] = v.y;
        xs[(d0 + 2) * 12 + r] = v.z;
        xs[(d0 + 3) * 12 + r] = v.w;
    }
    __syncthreads();
    int n  = tid & 255, q1 = tid >> 8;   // phase-1 role: n, d-chunk
    int d2 = tid & 127, q2 = tid >> 7;   // phase-2 role: d, n-chunk
    for (int i = 0; i < 2; ++i) {
        // ---- phase 1: th[r][n] = x[r].W[n] + b[n] + tphi ----
        const float* wti = wt + i * 32768;
        float acc[8] = {0,0,0,0,0,0,0,0};
        int dlo = q1 << 5;
        #pragma unroll 4
        for (int dd = 0; dd < 32; ++dd) {
            int d = dlo + dd;
            float wv = wti[d * 256 + n];
            float4 x0 = *(const float4*)&xs[d * 12];
            float4 x1 = *(const float4*)&xs[d * 12 + 4];
            acc[0] += x0.x * wv; acc[1] += x0.y * wv;
            acc[2] += x0.z * wv; acc[3] += x0.w * wv;
            acc[4] += x1.x * wv; acc[5] += x1.y * wv;
            acc[6] += x1.z * wv; acc[7] += x1.w * wv;
        }
        if (q1) {
            float* p = &red[(q1 - 1) * 2048 + n * 8];
            *(float4*)p       = make_float4(acc[0], acc[1], acc[2], acc[3]);
            *(float4*)(p + 4) = make_float4(acc[4], acc[5], acc[6], acc[7]);
        }
        __syncthreads();
        if (!q1) {
            #pragma unroll
            for (int qq = 0; qq < 3; ++qq) {
                const float* p = &red[qq * 2048 + n * 8];
                float4 p0 = *(const float4*)p;
                float4 p1 = *(const float4*)(p + 4);
                acc[0] += p0.x; acc[1] += p0.y; acc[2] += p0.z; acc[3] += p0.w;
                acc[4] += p1.x; acc[5] += p1.y; acc[6] += p1.z; acc[7] += p1.w;
            }
            float bv = lb[i * 256 + n];
            float cs[8], sn[8];
            #pragma unroll
            for (int r = 0; r < 8; ++r) {
                float th = acc[r] + bv + tphi;
                int idx = ((int)rintf(th * SCALE_F)) & 4095;
                float ang = (float)idx * STEP_F;
                cs[r] = __cosf(ang);
                sn[r] = __sinf(ang);
            }
            *(float4*)&csh[n * 12]     = make_float4(cs[0], cs[1], cs[2], cs[3]);
            *(float4*)&csh[n * 12 + 4] = make_float4(cs[4], cs[5], cs[6], cs[7]);
            *(float4*)&snh[n * 12]     = make_float4(sn[0], sn[1], sn[2], sn[3]);
            *(float4*)&snh[n * 12 + 4] = make_float4(sn[4], sn[5], sn[6], sn[7]);
        }
        __syncthreads();
        // ---- phase 2: o[r][d] = cs.Wr[d] + sn.Wi[d] ; x += silu(o) ----
        const float* wri = wrt + i * 32768;
        const float* wii = wit + i * 32768;
        float a2[8] = {0,0,0,0,0,0,0,0};
        int nlo = q2 << 5;
        #pragma unroll 2
        for (int k = 0; k < 32; ++k) {
            int nidx = nlo + k;
            float rv = wri[nidx * 128 + d2];
            float iv = wii[nidx * 128 + d2];
            float4 c0 = *(const float4*)&csh[nidx * 12];
            float4 c1 = *(const float4*)&csh[nidx * 12 + 4];
            float4 s0 = *(const float4*)&snh[nidx * 12];
            float4 s1 = *(const float4*)&snh[nidx * 12 + 4];
            a2[0] += c0.x * rv + s0.x * iv;
            a2[1] += c0.y * rv + s0.y * iv;
            a2[2] += c0.z * rv + s0.z * iv;
            a2[3] += c0.w * rv + s0.w * iv;
            a2[4] += c1.x * rv + s1.x * iv;
            a2[5] += c1.y * rv + s1.y * iv;
            a2[6] += c1.z * rv + s1.z * iv;
            a2[7] += c1.w * rv + s1.w * iv;
        }
        if (q2) {
            float* p = &red[(q2 - 1) * 1024 + d2 * 8];
            *(float4*)p       = make_float4(a2[0], a2[1], a2[2], a2[3]);
            *(float4*)(p + 4) = make_float4(a2[4], a2[5], a2[6], a2[7]);
        }
        __syncthreads();
        if (!q2) {
            #pragma unroll
            for (int qq = 0; qq < 7; ++qq) {
                const float* p = &red[qq * 1024 + d2 * 8];
                float4 p0 = *(const float4*)p;
                float4 p1 = *(const float4*)(p + 4);
                a2[0] += p0.x; a2[1] += p0.y; a2[2] += p0.z; a2[3] += p0.w;
                a2[4] += p1.x; a2[5] += p1.y; a2[6] += p1.z; a2[7] += p1.w;
            }
            float4 xv0 = *(const float4*)&xs[d2 * 12];
            float4 xv1 = *(const float4*)&xs[d2 * 12 + 4];
            float xv[8] = {xv0.x, xv0.y, xv0.z, xv0.w, xv1.x, xv1.y, xv1.z, xv1.w};
            #pragma unroll
            for (int r = 0; r < 8; ++r) {
                float o = a2[r];
                float sg = 1.0f / (1.0f + __expf(-o));
                xv[r] += o * sg;
            }
            *(float4*)&xs[d2 * 12]     = make_float4(xv[0], xv[1], xv[2], xv[3]);
            *(float4*)&xs[d2 * 12 + 4] = make_float4(xv[4], xv[5], xv[6], xv[7]);
        }
        __syncthreads();
    }
    if (tid < 256) {   // pack to bf16, restoring [r][d] order
        int r = tid >> 5, d0 = (tid & 31) << 2;
        float v0 = xs[(d0 + 0) * 12 + r];
        float v1 = xs[(d0 + 1) * 12 + r];
        float v2 = xs[(d0 + 2) * 12 + r];
        float v3 = xs[(d0 + 3) * 12 + r];
        unsigned int lo = ((unsigned)f2bf(v1) << 16) | f2bf(v0);
        unsigned int hi = ((unsigned)f2bf(v3) << 16) | f2bf(v2);
        ((uint2*)(X2bf + t * 1024))[tid] = make_uint2(lo, hi);
    }
}

// ---------------------------------------------------------------------------
// logits GEMM with SWAPPED MFMA operands: acc = mfma(W_frag, X_frag) computes
// C^T fragments, so each lane's 4 acc regs are 4 CONSECUTIVE v for one output
// row -> float4 stores, full-line write-combining (no NT, no amplification).
// Tile: 128 m x 256 v, 512 threads = 8 waves (2m x 4v), 32 KB LDS.
// ---------------------------------------------------------------------------
typedef short bhalf8 __attribute__((ext_vector_type(8)));
typedef float fx4    __attribute__((ext_vector_type(4)));

__global__ __launch_bounds__(512) void gemm_kernel(
        const unsigned short* __restrict__ X2bf,
        const unsigned short* __restrict__ outw_bf,
        float* __restrict__ out) {
    __shared__ __align__(16) unsigned short Ash[16384];   // 32 KB X tile
    int tid = threadIdx.x;
    int mt = blockIdx.x & 15;         // 16 m-tiles of 128 rows
    int vt = blockIdx.x >> 4;         // 197 v-tiles of 256 cols
    // stage X tile in B-operand fragment order: slot = (msub*4+ks)*64+lane
    for (int s = tid; s < 2048; s += 512) {
        int blk = s >> 6, ln = s & 63;
        int msub = blk >> 2, ks = blk & 3;
        int row = mt * 128 + msub * 16 + (ln & 15);
        int kel = ks * 32 + ((ln >> 4) << 3);
        ((int4*)Ash)[s] = *(const int4*)(X2bf + row * 128 + kel);
    }
    __syncthreads();
    int lane = tid & 63, wave = tid >> 6;
    int wm = wave >> 2;               // 0..1: m sub-tile (64 rows)
    int wn = wave & 3;                // 0..3: v sub-tile (64 cols)
    int ln15 = lane & 15, lq = lane >> 4;
    int vb = vt * 256 + wn * 64;
    fx4 acc[4][4] = {};               // [iv][jm]
    const bhalf8* Af = (const bhalf8*)Ash;
    #pragma unroll
    for (int ks = 0; ks < 4; ++ks) {
        bhalf8 xf[4];
        #pragma unroll
        for (int jm = 0; jm < 4; ++jm)
            xf[jm] = Af[((wm * 4 + jm) * 4 + ks) * 64 + lane];
        bhalf8 wf[4];
        #pragma unroll
        for (int iv = 0; iv < 4; ++iv) {
            int v = vb + iv * 16 + ln15;
            bhalf8 z = {};
            wf[iv] = z;
            if (v < VOC)
                wf[iv] = *(const bhalf8*)(outw_bf + v * 128 + ks * 32 + lq * 8);
        }
        #pragma unroll
        for (int iv = 0; iv < 4; ++iv) {
            #pragma unroll
            for (int jm = 0; jm < 4; ++jm)
                acc[iv][jm] = __builtin_amdgcn_mfma_f32_16x16x32_bf16(
                    wf[iv], xf[jm], acc[iv][jm], 0, 0, 0);
        }
    }
    // store: C^T fragment: col(ln15)=m, row(lq*4+reg)=v -> per-lane float4
    #pragma unroll
    for (int jm = 0; jm < 4; ++jm) {
        int m = mt * 128 + wm * 64 + jm * 16 + ln15;   // m = t*8 + b
        float* rp = out + (size_t)((m & 7) * SEQ + (m >> 3)) * VOC;
        #pragma unroll
        for (int iv = 0; iv < 4; ++iv) {
            int v4 = vb + iv * 16 + lq * 4;
            fx4 a = acc[iv][jm];
            if (v4 + 3 < VOC) {
                *(float4*)(rp + v4) = make_float4(a[0], a[1], a[2], a[3]);
            } else {
                #pragma unroll
                for (int e = 0; e < 4; ++e)
                    if (v4 + e < VOC) rp[v4 + e] = a[e];
            }
        }
    }
}

// ---------------------------------------------------------------------------
extern "C" void kernel_launch(void* const* d_in, const int* in_sizes, int n_in,
                              void* d_out, int out_size, void* d_ws, size_t ws_size,
                              hipStream_t stream) {
    const int*   ids  = (const int*)d_in[0];
    const float* emb  = (const float*)d_in[1];
    const float* W    = (const float*)d_in[2];
    const float* lb   = (const float*)d_in[3];
    const float* Wr   = (const float*)d_in[4];
    const float* Wi   = (const float*)d_in[5];
    const float* outw = (const float*)d_in[6];
    float* out = (float*)d_out;
    char* ws = (char*)d_ws;

    unsigned short* outw_bf = (unsigned short*)ws;            // 12,865,792 B
    float* wt    = (float*)(ws + 12865792);                   // 262,144 B
    float* wrt   = wt + 65536;                                // 262,144 B
    float* wit   = wrt + 65536;                               // 262,144 B
    float* X0    = wit + 65536;                               // 1,048,576 B
    unsigned short* X2bf = (unsigned short*)(X0 + 262144);    // 524,288 B

    prep_kernel<<<7059, 256, 0, stream>>>(emb, ids, W, Wr, Wi, outw,
                                          outw_bf, wt, wrt, wit, X0, out);
    layers_kernel<<<256, 1024, 0, stream>>>(X0, wt, wrt, wit, lb, X2bf);
    gemm_kernel<<<197 * 16, 512, 0, stream>>>(X2bf, outw_bf, out);
}